// Round 1
// baseline (471.287 us; speedup 1.0000x reference)
//
#include <hip/hip_runtime.h>
#include <hip/hip_bf16.h>

typedef unsigned long long u64;
typedef unsigned int u32;

#define NB   64
#define NPOS 1024
#define NOUT 25
#define NCLS 20

// ---- workspace layout (bytes); total ~9.7 MiB (assumes ws_size >= 10.5 MB) ----
#define OFF_W64   0          // double wT[512*25]   = 102400
#define OFF_B64   102400     // double b64[25]      = 200
#define OFF_ORDER 131072     // int   order[64*1024]        = 262144
#define OFF_SBOX  393216     // float4 sbox[64*1024]        = 1048576
#define OFF_SCLS  1441792    // int   scls[64*1024]         = 262144
#define OFF_VALID 1703936    // u64   validW[64*16]         = 8192
#define OFF_MASK  1712128    // u64   masks[64*1024*16]     = 8388608  -> end 10100736

// ---------------- kernel 0: convert weights to f64, transposed [c][o] ----------
__global__ __launch_bounds__(256) void k_cvt(const float* __restrict__ w,
                                             const float* __restrict__ bias,
                                             double* __restrict__ wT,
                                             double* __restrict__ b64)
{
    int idx = blockIdx.x * 256 + threadIdx.x;
    if (idx < 512 * NOUT) {
        int c = idx / NOUT, o = idx - c * NOUT;
        wT[idx] = (double)w[o * 512 + c];
    }
    if (idx < NOUT) b64[idx] = (double)bias[idx];
}

// ---------------- kernel 1: fused f64 GEMM + sigmoid/softmax/argmax + decode ---
__global__ __launch_bounds__(256) void k_main(const float* __restrict__ feat,
                                              const double* __restrict__ wT,
                                              const double* __restrict__ b64,
                                              float* __restrict__ boxes_out,
                                              float* __restrict__ scores_out,
                                              float* __restrict__ cls_out)
{
    const int b = blockIdx.y;
    const int n = blockIdx.x * 256 + threadIdx.x;
    const float* fp = feat + (size_t)b * 512 * NPOS + n;

    double acc[NOUT];
#pragma unroll
    for (int o = 0; o < NOUT; ++o) acc[o] = 0.0;

    float fa[16], fb[16];
#pragma unroll
    for (int u = 0; u < 16; ++u) fa[u] = fp[(size_t)u * NPOS];

    for (int c0 = 0; c0 < 512; c0 += 32) {
        // prefetch second half-block
#pragma unroll
        for (int u = 0; u < 16; ++u) fb[u] = fp[(size_t)(c0 + 16 + u) * NPOS];
        // compute first half-block (w via uniform scalar loads)
#pragma unroll
        for (int u = 0; u < 16; ++u) {
            double v = (double)fa[u];
            const double* wc = wT + (size_t)(c0 + u) * NOUT;
#pragma unroll
            for (int o = 0; o < NOUT; ++o) acc[o] = fma(v, wc[o], acc[o]);
        }
        if (c0 + 32 < 512) {
#pragma unroll
            for (int u = 0; u < 16; ++u) fa[u] = fp[(size_t)(c0 + 32 + u) * NPOS];
        }
#pragma unroll
        for (int u = 0; u < 16; ++u) {
            double v = (double)fb[u];
            const double* wc = wT + (size_t)(c0 + 16 + u) * NOUT;
#pragma unroll
            for (int o = 0; o < NOUT; ++o) acc[o] = fma(v, wc[o], acc[o]);
        }
    }

    double p[NOUT];
#pragma unroll
    for (int o = 0; o < NOUT; ++o) p[o] = acc[o] + b64[o];

    // conf = sigmoid(p0)
    double conf = 1.0 / (1.0 + exp(-p[0]));

    // softmax over p[1..20], argmax of conf*softmax (first max), score = max
    double m = p[1];
#pragma unroll
    for (int i = 2; i <= NCLS; ++i) m = fmax(m, p[i]);
    double e[NCLS];
    double s = 0.0;
#pragma unroll
    for (int i = 0; i < NCLS; ++i) { e[i] = exp(p[1 + i] - m); s += e[i]; }
    double best = -1.0; int ci = 0;
#pragma unroll
    for (int i = 0; i < NCLS; ++i) {
        double si = conf * (e[i] / s);
        if (si > best) { best = si; ci = i; }
    }

    // decode boxes (f64), grid cell
    int gx = n & 31, gy = n >> 5;
    double sx = 1.0 / (1.0 + exp(-p[21]));
    double sy = 1.0 / (1.0 + exp(-p[22]));
    double cx = (sx + (double)gx) * 32.0;
    double cy = (sy + (double)gy) * 32.0;
    double bw = exp(p[23]), bh = exp(p[24]);
    double x1 = (cx - bw * 0.5) * (1.0 / 1024.0);
    double y1 = (cy - bh * 0.5) * (1.0 / 1024.0);
    double x2 = (cx + bw * 0.5) * (1.0 / 1024.0);
    double y2 = (cy + bh * 0.5) * (1.0 / 1024.0);
    x1 = fmin(fmax(x1, 0.0), 1.0); y1 = fmin(fmax(y1, 0.0), 1.0);
    x2 = fmin(fmax(x2, 0.0), 1.0); y2 = fmin(fmax(y2, 0.0), 1.0);

    int gi = b * NPOS + n;
    ((float4*)boxes_out)[gi] = make_float4((float)x1, (float)y1, (float)x2, (float)y2);
    scores_out[gi] = (float)best;
    cls_out[gi]    = (float)ci;
}

// ---------------- kernel 2: per-batch bitonic sort (desc score, stable) -------
__global__ __launch_bounds__(256) void k_sort(const float* __restrict__ scores,
                                              const float* __restrict__ boxes,
                                              const float* __restrict__ cls,
                                              int* __restrict__ order,
                                              float4* __restrict__ sbox,
                                              int* __restrict__ scls,
                                              u64* __restrict__ validW)
{
    __shared__ u64 key[NPOS];
    __shared__ u64 vw[16];
    int b = blockIdx.x, tid = threadIdx.x;

    for (int ppos = tid; ppos < NPOS; ppos += 256) {
        u32 bits = __float_as_uint(scores[b * NPOS + ppos]);
        u32 d = ~(bits | 0x80000000u);   // descending-monotone key (scores >= 0)
        key[ppos] = ((u64)d << 32) | (u32)ppos;
    }
    if (tid < 16) vw[tid] = 0ull;
    __syncthreads();

    for (int k = 2; k <= NPOS; k <<= 1) {
        for (int j = k >> 1; j > 0; j >>= 1) {
            for (int idx = tid; idx < NPOS; idx += 256) {
                int l = idx ^ j;
                if (l > idx) {
                    u64 a = key[idx], c = key[l];
                    bool up = ((idx & k) == 0);
                    if ((a > c) == up) { key[idx] = c; key[l] = a; }
                }
            }
            __syncthreads();
        }
    }

    for (int ppos = tid; ppos < NPOS; ppos += 256) {
        u64 kk = key[ppos];
        int idx = (int)(kk & 0xffffffffu);
        order[b * NPOS + ppos] = idx;
        sbox [b * NPOS + ppos] = ((const float4*)boxes)[b * NPOS + idx];
        scls [b * NPOS + ppos] = (int)cls[b * NPOS + idx];
        u32 sb = (~(u32)(kk >> 32)) & 0x7fffffffu;
        float sc = __uint_as_float(sb);
        if (sc > 0.01f) atomicOr(&vw[ppos >> 6], 1ull << (ppos & 63));
    }
    __syncthreads();
    if (tid < 16) validW[b * 16 + tid] = vw[tid];
}

// ---------------- kernel 3: suppression bitmask build (upper triangle) --------
// block = 256 thr: 64 rows x 4 word-slots; grid = (16 rowblocks, 64 batches)
__global__ __launch_bounds__(256) void k_mask(const float4* __restrict__ sbox,
                                              const int* __restrict__ scls,
                                              u64* __restrict__ masks)
{
    __shared__ float4 boxl[NPOS];
    __shared__ float  arl[NPOS];
    __shared__ int    cll[NPOS];
    int b = blockIdx.y, rb = blockIdx.x, tid = threadIdx.x;

    for (int ppos = tid; ppos < NPOS; ppos += 256) {
        float4 bb = sbox[b * NPOS + ppos];
        boxl[ppos] = bb;
        arl[ppos] = (bb.z - bb.x) * (bb.w - bb.y);
        cll[ppos] = scls[b * NPOS + ppos];
    }
    __syncthreads();

    int i = rb * 64 + (tid >> 2);
    int wbase = tid & 3;
    float4 bi = boxl[i];
    float ai = arl[i];
    int ci_ = cll[i];
    u64* mrow = masks + ((size_t)(b * NPOS + i) << 4);

#pragma unroll
    for (int s = 0; s < 4; ++s) {
        int w = wbase + 4 * s;
        u64 bits = 0ull;
        if (w >= rb) {   // only j-words that can contain j > i
            for (int t = 0; t < 64; ++t) {
                int jj = (t + 2 * wbase) & 63;   // bank-conflict phase shift
                int j = w * 64 + jj;
                float4 bj = boxl[j];
                float xx1 = fmaxf(bi.x, bj.x), yy1 = fmaxf(bi.y, bj.y);
                float xx2 = fminf(bi.z, bj.z), yy2 = fminf(bi.w, bj.w);
                float ww = fmaxf(1e-28f, xx2 - xx1);
                float hh = fmaxf(1e-28f, yy2 - yy1);
                float inter = ww * hh;
                float uni = ai + arl[j] - inter;
                // same-class gate == class-offset boxes; mul-compare == iou>0.5
                bool sup = (cll[j] == ci_) && (uni > 0.0f) &&
                           (inter > 0.5f * uni) && (j > i);
                bits |= ((u64)sup) << jj;
            }
        }
        mrow[w] = bits;
    }
}

// ---------------- kernel 4: sequential suppression scan + scatter keep --------
// one wave (64 threads) per batch; lanes 0..15 own the 16 keep words
__global__ __launch_bounds__(64) void k_scan(const u64* __restrict__ validW,
                                             const u64* __restrict__ masks,
                                             const int* __restrict__ order,
                                             float* __restrict__ keep_out)
{
    int b = blockIdx.x, lane = threadIdx.x;
    u64 keep = (lane < 16) ? validW[b * 16 + lane] : 0ull;
    const u64* M = masks + (size_t)b * NPOS * 16;
    int myrow = lane >> 4;      // 0..3 : row within group of 4
    int myw = lane & 15;        // word within row

    u64 buf[8];
#pragma unroll
    for (int d = 0; d < 8; ++d)
        buf[d] = M[(d * 4 + myrow) * 16 + myw];   // groups 0..7

    for (int g0 = 0; g0 < 256; g0 += 8) {
#pragma unroll
        for (int d = 0; d < 8; ++d) {
            int g = g0 + d;
            u64 cur = buf[d];
            int gp = g + 8;
            buf[d] = (gp < 256) ? M[(gp * 4 + myrow) * 16 + myw] : 0ull;
            if (__any(cur != 0ull)) {            // any suppression in these 4 rows?
#pragma unroll
                for (int r = 0; r < 4; ++r) {
                    int i = g * 4 + r;
                    u64 kw = __shfl(keep, i >> 6);        // uniform broadcast
                    if ((kw >> (i & 63)) & 1ull) {        // row i still kept?
                        u64 mm = __shfl(cur, r * 16 + myw);
                        if (lane < 16) keep &= ~mm;
                    }
                }
            }
        }
    }

    // scatter keep bits back to original order as 0.0/1.0
#pragma unroll
    for (int t = 0; t < 16; ++t) {
        int ppos = t * 64 + lane;
        u64 kw = __shfl(keep, t);
        float v = ((kw >> lane) & 1ull) ? 1.0f : 0.0f;
        keep_out[b * NPOS + order[b * NPOS + ppos]] = v;
    }
}

// ------------------------------------------------------------------------------
extern "C" void kernel_launch(void* const* d_in, const int* in_sizes, int n_in,
                              void* d_out, int out_size, void* d_ws, size_t ws_size,
                              hipStream_t stream)
{
    const float* feat = (const float*)d_in[0];
    const float* w    = (const float*)d_in[1];
    const float* bias = (const float*)d_in[2];

    float* out = (float*)d_out;
    float* boxes_out  = out;                       // 64*1024*4
    float* scores_out = out + NB * NPOS * 4;       // 262144
    float* cls_out    = out + NB * NPOS * 5;       // 327680
    float* keep_out   = out + NB * NPOS * 6;       // 393216

    char* ws = (char*)d_ws;
    double* wT    = (double*)(ws + OFF_W64);
    double* b64   = (double*)(ws + OFF_B64);
    int*    order = (int*)   (ws + OFF_ORDER);
    float4* sbox  = (float4*)(ws + OFF_SBOX);
    int*    scls  = (int*)   (ws + OFF_SCLS);
    u64*    validW= (u64*)   (ws + OFF_VALID);
    u64*    masks = (u64*)   (ws + OFF_MASK);

    hipLaunchKernelGGL(k_cvt,  dim3(50),     dim3(256), 0, stream, w, bias, wT, b64);
    hipLaunchKernelGGL(k_main, dim3(4, 64),  dim3(256), 0, stream, feat, wT, b64,
                       boxes_out, scores_out, cls_out);
    hipLaunchKernelGGL(k_sort, dim3(64),     dim3(256), 0, stream, scores_out,
                       boxes_out, cls_out, order, sbox, scls, validW);
    hipLaunchKernelGGL(k_mask, dim3(16, 64), dim3(256), 0, stream, sbox, scls, masks);
    hipLaunchKernelGGL(k_scan, dim3(64),     dim3(64),  0, stream, validW, masks,
                       order, keep_out);
}